// Round 2
// baseline (110.049 us; speedup 1.0000x reference)
//
#include <hip/hip_runtime.h>

// labels[b,l,c] = argmin_q ( LN(t)[b,l,c] - LN(code_book)[c,q] )
//              = argmax_q LN(code_book)[c,q]        (tn constant along q)
//              = argmax_q code_book[c,q]            (global-scalar LN is monotone)
// => output is a 256-entry per-c label vector broadcast over (B, L).
//
// Fused single kernel: every block redundantly computes the 256 labels
// (one wave per 64 rows; 64 lanes cooperate per row: 4 coalesced loads +
// shfl_xor argmax butterfly), then writes its slice of the output.

#define C_DIM 256
#define Q_DIM 256
#define OUT_INT4 (4 * 512 * 256 / 4)   // B*L*C / 4 = 131072 int4 stores
#define NBLOCKS 128

__global__ __launch_bounds__(256) void rpq_fused(const float* __restrict__ cb,
                                                 int* __restrict__ out) {
    __shared__ int s[C_DIM];
    const int tid  = threadIdx.x;
    const int lane = tid & 63;
    const int wave = tid >> 6;

    // Each wave produces labels for rows [wave*64, wave*64+64).
    for (int r = wave * 64; r < wave * 64 + 64; ++r) {
        const float* row = cb + r * Q_DIM;
        // 4 coalesced loads: lane l covers q = l, 64+l, 128+l, 192+l.
        float v0 = row[lane];
        float v1 = row[64 + lane];
        float v2 = row[128 + lane];
        float v3 = row[192 + lane];
        // Within-thread: candidate indices strictly increase, so strict >
        // preserves first-index tie-breaking.
        float best = v0; int bi = lane;
        if (v1 > best) { best = v1; bi = 64 + lane; }
        if (v2 > best) { best = v2; bi = 128 + lane; }
        if (v3 > best) { best = v3; bi = 192 + lane; }
        // Wave argmax butterfly; on ties take the smaller index
        // (matches jnp.argmin's first-min semantics).
        #pragma unroll
        for (int off = 32; off > 0; off >>= 1) {
            float ov = __shfl_xor(best, off);
            int   oi = __shfl_xor(bi, off);
            if (ov > best || (ov == best && oi < bi)) { best = ov; bi = oi; }
        }
        if (lane == 0) s[r] = bi;
    }
    __syncthreads();

    // Each thread's int4 payload is invariant across its grid-stride stores:
    // int4 index i covers ints 4i..4i+3, and (4i) mod 256 == (tid&63)*4 for
    // every i in this thread's stride sequence (stride 32768 ≡ 0 mod 64).
    const int base = (lane) * 4 & (C_DIM - 1);
    const int4 v = make_int4(s[base], s[base + 1], s[base + 2], s[base + 3]);
    int4* o4 = (int4*)out;
    for (int i = blockIdx.x * blockDim.x + tid; i < OUT_INT4; i += NBLOCKS * 256) {
        o4[i] = v;
    }
}

extern "C" void kernel_launch(void* const* d_in, const int* in_sizes, int n_in,
                              void* d_out, int out_size, void* d_ws, size_t ws_size,
                              hipStream_t stream) {
    // inputs: 0=input_values (B,L,D) f32, 1=W (Q,D) f32, 2=code_book (C,Q) f32, 3=raw_signal
    const float* code_book = (const float*)d_in[2];
    int* out = (int*)d_out;
    rpq_fused<<<NBLOCKS, 256, 0, stream>>>(code_book, out);
}

// Round 3
// 67.991 us; speedup vs baseline: 1.6186x; 1.6186x over previous
//
#include <hip/hip_runtime.h>

// labels[b,l,c] = argmin_q ( LN(t)[b,l,c] - LN(code_book)[c,q] )
//              = argmax_q LN(code_book)[c,q]        (tn constant along q)
//              = argmax_q code_book[c,q]            (global-scalar LN is monotone)
// => output is a 256-entry per-c label vector broadcast over (B, L).
//
// Single kernel; each block redundantly computes the 256 labels with ONE
// THREAD PER ROW (64 independent float4 loads -> in-register scan; no
// cross-lane ops, no per-iteration memory waits), then writes its slice.
// Redundant codebook reads are L2-resident (256 KB/block).

#define C_DIM 256
#define Q_DIM 256
#define OUT_INT4 (4 * 512 * 256 / 4)   // B*L*C / 4 = 131072 int4 stores
#define NBLOCKS 128

__global__ __launch_bounds__(256) void rpq_fused(const float* __restrict__ cb,
                                                 int* __restrict__ out) {
    __shared__ int s[C_DIM];
    const int tid  = threadIdx.x;
    const int lane = tid & 63;

    // Thread tid scans row tid. Strict > in ascending q order reproduces
    // jnp.argmin's first-index tie-breaking.
    const float4* row4 = (const float4*)(cb + tid * Q_DIM);
    float best = -3.4e38f;
    int bi = 0;
#pragma unroll 8
    for (int j = 0; j < Q_DIM / 4; ++j) {
        float4 v = row4[j];
        int q = j * 4;
        if (v.x > best) { best = v.x; bi = q; }
        if (v.y > best) { best = v.y; bi = q + 1; }
        if (v.z > best) { best = v.z; bi = q + 2; }
        if (v.w > best) { best = v.w; bi = q + 3; }
    }
    s[tid] = bi;
    __syncthreads();

    // Each thread's int4 payload is invariant across its grid-stride stores:
    // for i = blk*256 + tid + k*32768, (4i) mod 256 == 4*(tid & 63).
    const int base = lane * 4;
    const int4 v = make_int4(s[base], s[base + 1], s[base + 2], s[base + 3]);
    int4* o4 = (int4*)out;
    for (int i = blockIdx.x * blockDim.x + tid; i < OUT_INT4; i += NBLOCKS * 256) {
        o4[i] = v;
    }
}

extern "C" void kernel_launch(void* const* d_in, const int* in_sizes, int n_in,
                              void* d_out, int out_size, void* d_ws, size_t ws_size,
                              hipStream_t stream) {
    // inputs: 0=input_values (B,L,D) f32, 1=W (Q,D) f32, 2=code_book (C,Q) f32, 3=raw_signal
    const float* code_book = (const float*)d_in[2];
    int* out = (int*)d_out;
    rpq_fused<<<NBLOCKS, 256, 0, stream>>>(code_book, out);
}